// Round 15
// baseline (195.896 us; speedup 1.0000x reference)
//
#include <hip/hip_runtime.h>
#include <math.h>

typedef unsigned short u16;
typedef unsigned int u32;
typedef __bf16 bf16x8 __attribute__((ext_vector_type(8)));
typedef float f32x4 __attribute__((ext_vector_type(4)));
typedef float f32x2 __attribute__((ext_vector_type(2)));

// B=4, L=2048, D_MODEL=512, D_INNER=1024, D_STATE=16, D_CONV=4, DT_RANK=32
#define LSEQ 2048
#define BL_TOT 8192            // B*L

#if __has_builtin(__builtin_amdgcn_exp2f)
#define EXP2(x) __builtin_amdgcn_exp2f(x)
#else
#define EXP2(x) exp2f(x)
#endif
#define LOG2E 1.44269504088896f

__device__ __forceinline__ float bf2f(u16 h) { return __uint_as_float(((u32)h) << 16); }
__device__ __forceinline__ u16 f2bf(float f) {
  u32 u = __float_as_uint(f);
  u32 r = (u + 0x7fffu + ((u >> 16) & 1u)) >> 16;
  return (u16)r;
}

// async global->LDS, 16B per lane (lds dest = wave-uniform base + lane*16)
__device__ __forceinline__ void async_cp16(const void* g, void* l) {
  __builtin_amdgcn_global_load_lds(
      (const __attribute__((address_space(1))) unsigned int*)g,
      (__attribute__((address_space(3))) unsigned int*)l, 16, 0, 0);
}

__device__ __forceinline__ void cast4(const float* __restrict__ in,
                                      u16* __restrict__ out, int i) {
  const float4 v = ((const float4*)in)[i];
  uint2 o;
  o.x = (u32)f2bf(v.x) | ((u32)f2bf(v.y) << 16);
  o.y = (u32)f2bf(v.z) | ((u32)f2bf(v.w) << 16);
  ((uint2*)out)[i] = o;
}

// ---------------- fused prep: all input casts + A-table + geom flag --------
// seg5 (blk==5728) is a SINGLE block: computes An2/a0tab and the geom flag
// via ballot+LDS reduce, writing flag exactly once -> no memset needed.
__global__ __launch_bounds__(256) void prep_kernel(
    const float* __restrict__ hs, u16* __restrict__ hs_bf,
    const float* __restrict__ Win, u16* __restrict__ win_bf,
    const float* __restrict__ Wx, u16* __restrict__ wx_bf,
    const float* __restrict__ Wdt, u16* __restrict__ wdt_bf,
    const float* __restrict__ Wout, u16* __restrict__ wout_bf,
    const float* __restrict__ A_log, float* __restrict__ An2,
    float* __restrict__ a0tab, int* __restrict__ flag)
{
  __shared__ int anyv;
  const int blk = blockIdx.x;
  const int tid = threadIdx.x;
  if (blk < 4096) {
    cast4(hs, hs_bf, blk * 256 + tid);
  } else if (blk < 5120) {
    cast4(Win, win_bf, (blk - 4096) * 256 + tid);
  } else if (blk < 5184) {
    cast4(Wx, wx_bf, (blk - 5120) * 256 + tid);
  } else if (blk < 5216) {
    cast4(Wdt, wdt_bf, (blk - 5184) * 256 + tid);
  } else if (blk < 5728) {
    cast4(Wout, wout_bf, (blk - 5216) * 256 + tid);
  } else {
    // single block: An2 + a0tab + geom flag (16384 elems, 64 iters/thread)
    if (tid == 0) anyv = 0;
    __syncthreads();
    bool viol = false;
    for (int it = 0; it < 64; ++it) {
      const int i = it * 256 + tid;
      const float v = -__expf(A_log[i]) * LOG2E;
      An2[i] = v;
      const int dd = i >> 4, n = i & 15;
      const float a0 = -__expf(A_log[dd * 16]) * LOG2E;
      if (n == 0) a0tab[dd] = a0;
      const float ev = (n + 1) * a0;
      viol |= (fabsf(v - ev) > 4e-6f * fabsf(ev));
    }
    const unsigned long long m = __ballot(viol);
    if ((tid & 63) == 0 && m != 0ull) anyv = 1;
    __syncthreads();
    if (tid == 0) *flag = anyv ? 0 : 1;   // 1 => geometric structure holds
  }
}

// ---------------- bf16 MFMA GEMM: C[M,N] = A[M,K] * B[N,K]^T ----------------
// 128x128 tile, 4 waves, BK=32 (linear LDS) or BK=64 (XOR-swizzled LDS:
// phys 16B-slot = logical ^ (row&7); write side = pre-swizzled global src,
// read side = same XOR -> 2-way banks, rule #21 both-sides). K-split via
// gridDim.z (kper per slice, czstride = f32 elems per z slice, EPI==0 only).
// SWZ: bijective XCD swizzle of flat block id (needs nwg % 8 == 0).
// EPI: 0 = f32 store, 1 = bf16 store, 2 = softplus(acc + bias[n]) -> bf16
template<int EPI, bool SWZ, int BK>
__global__ __launch_bounds__(256) void gemm_bf16_kernel(
    const u16* __restrict__ A, int lda,
    const u16* __restrict__ B, int ldb,
    void* __restrict__ C, int ldc,
    int N, int kper, const float* __restrict__ bias, size_t czstride)
{
  __shared__ alignas(1024) u16 As[128][BK];
  __shared__ alignas(1024) u16 Bs[128][BK];
  const int tid = threadIdx.x;
  int bx = blockIdx.x, by = blockIdx.y;
  if (SWZ) {
    const u32 gx = gridDim.x;
    const u32 nwg = gx * gridDim.y;
    const u32 flat = (u32)by * gx + bx;
    const u32 cpx = nwg >> 3;
    const u32 swz = (flat & 7) * cpx + (flat >> 3);
    bx = swz % gx;
    by = swz / gx;
  }
  const int row0 = by * 128;
  const int col0 = bx * 128;
  const int kz0 = blockIdx.z * kper;
  const int wave = tid >> 6, lane = tid & 63;
  const int wr = (wave >> 1) * 64;   // wave row offset in tile
  const int wc = (wave & 1) * 64;    // wave col offset in tile
  const int lr = lane & 15, lk = lane >> 4;

  f32x4 acc[4][4] = {};

  if (BK == 64) {
    const int srow = wave * 32 + (lane >> 3);
    const int scol = ((lane & 7) ^ (lane >> 3)) * 8;
    const u16* ag = A + (size_t)(row0 + srow) * lda + scol;
    const u16* bg = B + (size_t)(col0 + srow) * ldb + scol;
    u16* al = &As[0][0] + wave * 2048;     // u16 elems (wave*4KB)
    u16* bl = &Bs[0][0] + wave * 2048;
    const int lr7 = lr & 7;

    for (int k0 = kz0; k0 < kz0 + kper; k0 += 64) {
      __syncthreads();
      #pragma unroll
      for (int s = 0; s < 4; ++s) {
        async_cp16(ag + (size_t)s * 8 * lda + k0, al + s * 512);
        async_cp16(bg + (size_t)s * 8 * ldb + k0, bl + s * 512);
      }
      __syncthreads();
      bf16x8 af[2][4], bfr[2][4];
      #pragma unroll
      for (int kk = 0; kk < 2; ++kk)
        #pragma unroll
        for (int i = 0; i < 4; ++i) {
          af[kk][i]  = *(const bf16x8*)&As[wr + i * 16 + lr][(((kk << 2) | lk) ^ lr7) * 8];
          bfr[kk][i] = *(const bf16x8*)&Bs[wc + i * 16 + lr][(((kk << 2) | lk) ^ lr7) * 8];
        }
      #pragma unroll
      for (int i = 0; i < 4; ++i)
        #pragma unroll
        for (int j = 0; j < 4; ++j) {
          acc[i][j] = __builtin_amdgcn_mfma_f32_16x16x32_bf16(af[0][i], bfr[0][j], acc[i][j], 0, 0, 0);
          acc[i][j] = __builtin_amdgcn_mfma_f32_16x16x32_bf16(af[1][i], bfr[1][j], acc[i][j], 0, 0, 0);
        }
    }
  } else {
    const int srow = wave * 32 + (lane >> 2);
    const int scol = (lane & 3) * 8;
    const u16* ag0 = A + (size_t)(row0 + srow) * lda + scol;
    const u16* ag1 = A + (size_t)(row0 + srow + 16) * lda + scol;
    const u16* bg0 = B + (size_t)(col0 + srow) * ldb + scol;
    const u16* bg1 = B + (size_t)(col0 + srow + 16) * ldb + scol;
    u16* al0 = &As[0][0] + wave * 1024;
    u16* al1 = &As[0][0] + wave * 1024 + 512;
    u16* bl0 = &Bs[0][0] + wave * 1024;
    u16* bl1 = &Bs[0][0] + wave * 1024 + 512;

    for (int k0 = kz0; k0 < kz0 + kper; k0 += 32) {
      __syncthreads();
      async_cp16(ag0 + k0, al0);
      async_cp16(ag1 + k0, al1);
      async_cp16(bg0 + k0, bl0);
      async_cp16(bg1 + k0, bl1);
      __syncthreads();
      bf16x8 af[4], bfr[4];
      #pragma unroll
      for (int i = 0; i < 4; ++i) {
        af[i]  = *(const bf16x8*)&As[wr + i * 16 + lr][lk * 8];
        bfr[i] = *(const bf16x8*)&Bs[wc + i * 16 + lr][lk * 8];
      }
      #pragma unroll
      for (int i = 0; i < 4; ++i)
        #pragma unroll
        for (int j = 0; j < 4; ++j)
          acc[i][j] = __builtin_amdgcn_mfma_f32_16x16x32_bf16(af[i], bfr[j], acc[i][j], 0, 0, 0);
    }
  }

  float* Cf = (float*)C + blockIdx.z * czstride;
  // C/D layout (HW-verified): col = lane&15, row = (lane>>4)*4 + reg
  #pragma unroll
  for (int i = 0; i < 4; ++i) {
    #pragma unroll
    for (int j = 0; j < 4; ++j) {
      #pragma unroll
      for (int q = 0; q < 4; ++q) {
        const int r = row0 + wr + i * 16 + lk * 4 + q;
        const int c = col0 + wc + j * 16 + lr;
        if (c < N) {
          float v = acc[i][j][q];
          const size_t o = (size_t)r * ldc + c;
          if (EPI == 0) {
            Cf[o] = v;
          } else if (EPI == 1) {
            ((u16*)C)[o] = f2bf(v);
          } else {
            v += bias[c];
            v = (v > 20.f) ? v : log1pf(__expf(v));
            ((u16*)C)[o] = f2bf(v);
          }
        }
      }
    }
  }
}

// ---------------- reduce 4 K-split partials -> xdbl_f (f32) + xdbl_bf ------
__global__ __launch_bounds__(256) void reduce_xdbl_kernel(
    const float* __restrict__ parts, float* __restrict__ xf, u16* __restrict__ xbf)
{
  const int i = blockIdx.x * 256 + threadIdx.x;   // 131072 float4 slots
  const int S = BL_TOT * 64 / 4;                  // float4 stride per slice
  const float4 a = ((const float4*)parts)[i];
  const float4 b = ((const float4*)parts)[i + S];
  const float4 c = ((const float4*)parts)[i + 2 * S];
  const float4 d = ((const float4*)parts)[i + 3 * S];
  float4 s;
  s.x = (a.x + b.x) + (c.x + d.x);
  s.y = (a.y + b.y) + (c.y + d.y);
  s.z = (a.z + b.z) + (c.z + d.z);
  s.w = (a.w + b.w) + (c.w + d.w);
  ((float4*)xf)[i] = s;
  uint2 o;
  o.x = (u32)f2bf(s.x) | ((u32)f2bf(s.y) << 16);
  o.y = (u32)f2bf(s.z) | ((u32)f2bf(s.w) << 16);
  ((uint2*)xbf)[i] = o;
}

// ---------------- depthwise causal conv1d (k=4) + SiLU ----------------
#define CONV_T 16
__global__ __launch_bounds__(256) void conv_silu_kernel(
    const u16* __restrict__ xz, const float* __restrict__ cw,
    const float* __restrict__ cb, u16* __restrict__ u)
{
  const int d = (blockIdx.x & 3) * 256 + threadIdx.x;
  const int strip = (blockIdx.x >> 2) & (LSEQ / CONV_T - 1);
  const int b = blockIdx.x >> 9;            // 4*128*4 = 2048 blocks
  const int t0 = strip * CONV_T;
  const float4 w = *(const float4*)(cw + d * 4);
  const float bias = cb[d];
  const u16* xp = xz + ((size_t)b * LSEQ + t0) * 2048 + d;
  u16* up = u + ((size_t)b * LSEQ + t0) * 1024 + d;
  float x0 = (t0 >= 3) ? bf2f(xp[-3 * 2048]) : 0.f;
  float x1 = (t0 >= 2) ? bf2f(xp[-2 * 2048]) : 0.f;
  float x2 = (t0 >= 1) ? bf2f(xp[-1 * 2048]) : 0.f;
  #pragma unroll
  for (int t = 0; t < CONV_T; ++t) {
    const float x3 = bf2f(xp[(size_t)t * 2048]);
    float a = bias + x0 * w.x + x1 * w.y + x2 * w.z + x3 * w.w;
    a = a / (1.f + EXP2(a * -LOG2E));
    up[(size_t)t * 1024] = f2bf(a);
    x0 = x1; x1 = x2; x2 = x3;
  }
}

// ---------------- selective scan, chunked, full-channel-per-thread ----------
// 128-thread blocks (2 waves). One thread owns all 16 states (8x f32x2).
// B/C base derives from blockIdx ONLY -> scalar s_load path.
// hend/hinit layout: [chunk][4096 ch][16 n].
template<int CHLEN>
__global__ __launch_bounds__(128) void scan_pass1(
    const u16* __restrict__ delta, const u16* __restrict__ u,
    const float* __restrict__ xdf, const float* __restrict__ An2,
    const float* __restrict__ a0tab, const int* __restrict__ geomflag,
    float* __restrict__ hend, float* __restrict__ sumdelta)
{
  const int chunk = blockIdx.x >> 5;
  const int g = blockIdx.x & 31;
  const int b = g >> 3;                          // uniform (blockIdx only)
  const int d = (g & 7) * 128 + threadIdx.x;     // 0..1023
  const int ch = g * 128 + threadIdx.x;          // b*1024 + d
  const int geom = *geomflag;
  float sumd = 0.f;
  const size_t base = (size_t)b * LSEQ + (size_t)chunk * CHLEN;  // uniform
  const u16* dp = delta + base * 1024 + d;
  const u16* up = u + base * 1024 + d;
  const float* xd = xdf + base * 64 + 32;   // uniform -> s_load path
  f32x2 h0 = {0,0}, h1 = {0,0}, h2v = {0,0}, h3 = {0,0};
  f32x2 h4 = {0,0}, h5 = {0,0}, h6 = {0,0}, h7 = {0,0};
  if (geom) {
    const float a0 = a0tab[d];
    #pragma unroll 4
    for (int t = 0; t < CHLEN; ++t) {
      const float dt = bf2f(dp[(size_t)t * 1024]);
      const float ut = bf2f(up[(size_t)t * 1024]);
      const float du = dt * ut;
      const float* bt = xd + (size_t)t * 64;
      const float E = EXP2(dt * a0);
      const float p2 = E * E,  p3 = p2 * E,  p4 = p2 * p2;
      const float p5 = p4 * E, p6 = p4 * p2, p7 = p4 * p3, p8 = p4 * p4;
      const float p9 = p8 * E, p10 = p8 * p2, p11 = p8 * p3, p12 = p8 * p4;
      const float p13 = p8 * p5, p14 = p8 * p6, p15 = p8 * p7, p16 = p8 * p8;
      const f32x2 du2 = {du, du};
      h0 = h0 * (f32x2){E,   p2}  + du2 * *(const f32x2*)(bt + 0);
      h1 = h1 * (f32x2){p3,  p4}  + du2 * *(const f32x2*)(bt + 2);
      h2v = h2v * (f32x2){p5, p6} + du2 * *(const f32x2*)(bt + 4);
      h3 = h3 * (f32x2){p7,  p8}  + du2 * *(const f32x2*)(bt + 6);
      h4 = h4 * (f32x2){p9,  p10} + du2 * *(const f32x2*)(bt + 8);
      h5 = h5 * (f32x2){p11, p12} + du2 * *(const f32x2*)(bt + 10);
      h6 = h6 * (f32x2){p13, p14} + du2 * *(const f32x2*)(bt + 12);
      h7 = h7 * (f32x2){p15, p16} + du2 * *(const f32x2*)(bt + 14);
      sumd += dt;
    }
  } else {
    float A2[16];
    #pragma unroll
    for (int q = 0; q < 4; ++q)
      *(float4*)&A2[4*q] = ((const float4*)(An2 + d * 16))[q];
    for (int t = 0; t < CHLEN; ++t) {
      const float dt = bf2f(dp[(size_t)t * 1024]);
      const float ut = bf2f(up[(size_t)t * 1024]);
      const float du = dt * ut;
      const float* bt = xd + (size_t)t * 64;
      const f32x2 du2 = {du, du};
      h0 = h0 * (f32x2){EXP2(dt*A2[0]), EXP2(dt*A2[1])}   + du2 * *(const f32x2*)(bt + 0);
      h1 = h1 * (f32x2){EXP2(dt*A2[2]), EXP2(dt*A2[3])}   + du2 * *(const f32x2*)(bt + 2);
      h2v = h2v * (f32x2){EXP2(dt*A2[4]), EXP2(dt*A2[5])} + du2 * *(const f32x2*)(bt + 4);
      h3 = h3 * (f32x2){EXP2(dt*A2[6]), EXP2(dt*A2[7])}   + du2 * *(const f32x2*)(bt + 6);
      h4 = h4 * (f32x2){EXP2(dt*A2[8]), EXP2(dt*A2[9])}   + du2 * *(const f32x2*)(bt + 8);
      h5 = h5 * (f32x2){EXP2(dt*A2[10]), EXP2(dt*A2[11])} + du2 * *(const f32x2*)(bt + 10);
      h6 = h6 * (f32x2){EXP2(dt*A2[12]), EXP2(dt*A2[13])} + du2 * *(const f32x2*)(bt + 12);
      h7 = h7 * (f32x2){EXP2(dt*A2[14]), EXP2(dt*A2[15])} + du2 * *(const f32x2*)(bt + 14);
      sumd += dt;
    }
  }
  float* he = hend + ((size_t)chunk * 4096 + ch) * 16;
  ((f32x2*)he)[0] = h0;  ((f32x2*)he)[1] = h1;
  ((f32x2*)he)[2] = h2v; ((f32x2*)he)[3] = h3;
  ((f32x2*)he)[4] = h4;  ((f32x2*)he)[5] = h5;
  ((f32x2*)he)[6] = h6;  ((f32x2*)he)[7] = h7;
  sumdelta[(size_t)chunk * 4096 + ch] = sumd;
}

// pass2: sequential chunk-stitch, IN PLACE (buf: hend in, hinit out)
__global__ __launch_bounds__(256) void scan_pass2(
    const float* __restrict__ An2, const float* __restrict__ sumdelta,
    float* __restrict__ buf, int nchunk)
{
  const int idx = blockIdx.x * 256 + threadIdx.x;  // 65536 = 4096 ch * 16 n
  const int ch = idx >> 4, n = idx & 15;
  const int d = ch & 1023;
  const float A2 = An2[d * 16 + n];
  float h = 0.f;
  #pragma unroll 4
  for (int c = 0; c < nchunk; ++c) {
    const size_t o = (size_t)c * 4096 + ch;
    const float he = buf[o * 16 + n];
    const float e = EXP2(A2 * sumdelta[o]);   // indep of h -> pipelines ahead
    buf[o * 16 + n] = h;       // hinit for chunk c
    h = e * h + he;
  }
}

// pass3: recompute with correct h_init; y = (<h,C> + u*D) * silu(z) -> bf16
// NOTE: y aliases delta. Safe: each (bl,d) element is read then written by
// the SAME thread (read-before-write, data dependence through the dot).
template<int CHLEN>
__global__ __launch_bounds__(128) void scan_pass3(
    const u16* __restrict__ delta, const u16* __restrict__ u,
    const float* __restrict__ xdf, const u16* __restrict__ xz,
    const float* __restrict__ An2, const float* __restrict__ a0tab,
    const int* __restrict__ geomflag, const float* __restrict__ Dvec,
    const float* __restrict__ hinit, u16* __restrict__ y)
{
  const int chunk = blockIdx.x >> 5;
  const int g = blockIdx.x & 31;
  const int b = g >> 3;                          // uniform (blockIdx only)
  const int d = (g & 7) * 128 + threadIdx.x;
  const int ch = g * 128 + threadIdx.x;
  const int geom = *geomflag;
  f32x2 h0, h1, h2v, h3, h4, h5, h6, h7;
  {
    const f32x2* hi = (const f32x2*)(hinit + ((size_t)chunk * 4096 + ch) * 16);
    h0 = hi[0]; h1 = hi[1]; h2v = hi[2]; h3 = hi[3];
    h4 = hi[4]; h5 = hi[5]; h6 = hi[6]; h7 = hi[7];
  }
  const float Dd = Dvec[d];
  const size_t base = (size_t)b * LSEQ + (size_t)chunk * CHLEN;  // uniform
  const u16* dp = delta + base * 1024 + d;
  const u16* up = u + base * 1024 + d;
  const float* xd = xdf + base * 64 + 32;   // uniform -> s_load path
  const u16* zp = xz + base * 2048 + 1024 + d;
  u16* yp = y + base * 1024 + d;
  if (geom) {
    const float a0 = a0tab[d];
    #pragma unroll 4
    for (int t = 0; t < CHLEN; ++t) {
      const float dt = bf2f(dp[(size_t)t * 1024]);
      const float ut = bf2f(up[(size_t)t * 1024]);
      const float du = dt * ut;
      const float* bt = xd + (size_t)t * 64;
      const float E = EXP2(dt * a0);
      const float p2 = E * E,  p3 = p2 * E,  p4 = p2 * p2;
      const float p5 = p4 * E, p6 = p4 * p2, p7 = p4 * p3, p8 = p4 * p4;
      const float p9 = p8 * E, p10 = p8 * p2, p11 = p8 * p3, p12 = p8 * p4;
      const float p13 = p8 * p5, p14 = p8 * p6, p15 = p8 * p7, p16 = p8 * p8;
      const f32x2 du2 = {du, du};
      h0 = h0 * (f32x2){E,   p2}  + du2 * *(const f32x2*)(bt + 0);
      h1 = h1 * (f32x2){p3,  p4}  + du2 * *(const f32x2*)(bt + 2);
      h2v = h2v * (f32x2){p5, p6} + du2 * *(const f32x2*)(bt + 4);
      h3 = h3 * (f32x2){p7,  p8}  + du2 * *(const f32x2*)(bt + 6);
      h4 = h4 * (f32x2){p9,  p10} + du2 * *(const f32x2*)(bt + 8);
      h5 = h5 * (f32x2){p11, p12} + du2 * *(const f32x2*)(bt + 10);
      h6 = h6 * (f32x2){p13, p14} + du2 * *(const f32x2*)(bt + 12);
      h7 = h7 * (f32x2){p15, p16} + du2 * *(const f32x2*)(bt + 14);
      f32x2 a0v = h0 * *(const f32x2*)(bt + 16);
      f32x2 a1v = h1 * *(const f32x2*)(bt + 18);
      f32x2 a2v = h2v * *(const f32x2*)(bt + 20);
      f32x2 a3v = h3 * *(const f32x2*)(bt + 22);
      a0v = a0v + h4 * *(const f32x2*)(bt + 24);
      a1v = a1v + h5 * *(const f32x2*)(bt + 26);
      a2v = a2v + h6 * *(const f32x2*)(bt + 28);
      a3v = a3v + h7 * *(const f32x2*)(bt + 30);
      const f32x2 s01 = (a0v + a1v) + (a2v + a3v);
      const float pv = s01.x + s01.y;
      const float z = bf2f(zp[(size_t)t * 2048]);
      const float sig = 1.f / (1.f + EXP2(z * -LOG2E));
      const float yy = (pv + ut * Dd) * (z * sig);
      yp[(size_t)t * 1024] = f2bf(yy);
    }
  } else {
    float A2[16];
    #pragma unroll
    for (int q = 0; q < 4; ++q)
      *(float4*)&A2[4*q] = ((const float4*)(An2 + d * 16))[q];
    for (int t = 0; t < CHLEN; ++t) {
      const float dt = bf2f(dp[(size_t)t * 1024]);
      const float ut = bf2f(up[(size_t)t * 1024]);
      const float du = dt * ut;
      const float* bt = xd + (size_t)t * 64;
      const f32x2 du2 = {du, du};
      h0 = h0 * (f32x2){EXP2(dt*A2[0]), EXP2(dt*A2[1])}   + du2 * *(const f32x2*)(bt + 0);
      h1 = h1 * (f32x2){EXP2(dt*A2[2]), EXP2(dt*A2[3])}   + du2 * *(const f32x2*)(bt + 2);
      h2v = h2v * (f32x2){EXP2(dt*A2[4]), EXP2(dt*A2[5])} + du2 * *(const f32x2*)(bt + 4);
      h3 = h3 * (f32x2){EXP2(dt*A2[6]), EXP2(dt*A2[7])}   + du2 * *(const f32x2*)(bt + 6);
      h4 = h4 * (f32x2){EXP2(dt*A2[8]), EXP2(dt*A2[9])}   + du2 * *(const f32x2*)(bt + 8);
      h5 = h5 * (f32x2){EXP2(dt*A2[10]), EXP2(dt*A2[11])} + du2 * *(const f32x2*)(bt + 10);
      h6 = h6 * (f32x2){EXP2(dt*A2[12]), EXP2(dt*A2[13])} + du2 * *(const f32x2*)(bt + 12);
      h7 = h7 * (f32x2){EXP2(dt*A2[14]), EXP2(dt*A2[15])} + du2 * *(const f32x2*)(bt + 14);
      f32x2 a0v = h0 * *(const f32x2*)(bt + 16);
      f32x2 a1v = h1 * *(const f32x2*)(bt + 18);
      f32x2 a2v = h2v * *(const f32x2*)(bt + 20);
      f32x2 a3v = h3 * *(const f32x2*)(bt + 22);
      a0v = a0v + h4 * *(const f32x2*)(bt + 24);
      a1v = a1v + h5 * *(const f32x2*)(bt + 26);
      a2v = a2v + h6 * *(const f32x2*)(bt + 28);
      a3v = a3v + h7 * *(const f32x2*)(bt + 30);
      const f32x2 s01 = (a0v + a1v) + (a2v + a3v);
      const float pv = s01.x + s01.y;
      const float z = bf2f(zp[(size_t)t * 2048]);
      const float sig = 1.f / (1.f + EXP2(z * -LOG2E));
      const float yy = (pv + ut * Dd) * (z * sig);
      yp[(size_t)t * 1024] = f2bf(yy);
    }
  }
}

extern "C" void kernel_launch(void* const* d_in, const int* in_sizes, int n_in,
                              void* d_out, int out_size, void* d_ws, size_t ws_size,
                              hipStream_t stream)
{
  (void)in_sizes; (void)n_in; (void)out_size;
  const float* hs    = (const float*)d_in[0];
  const float* Win   = (const float*)d_in[1];
  const float* convw = (const float*)d_in[2];
  const float* convb = (const float*)d_in[3];
  const float* Wx    = (const float*)d_in[4];
  const float* Wdt   = (const float*)d_in[5];
  const float* bdt   = (const float*)d_in[6];
  const float* Alog  = (const float*)d_in[7];
  const float* Dv    = (const float*)d_in[8];
  const float* Wout  = (const float*)d_in[9];

  char* p = (char*)d_ws;
  auto take = [&](size_t bytes) -> char* {
    char* r = p; p += (bytes + 255) & ~(size_t)255; return r;
  };
  u16* hs_bf    = (u16*)take((size_t)BL_TOT * 512 * 2);   // 8 MB (dead after K1)
  u16* win_bf   = (u16*)take((size_t)2048 * 512 * 2);     // 2 MB (dead after K1)
  u16* wx_bf    = (u16*)take((size_t)64 * 1024 * 2);
  u16* wdt_bf   = (u16*)take((size_t)1024 * 32 * 2);
  u16* wout_bf  = (u16*)take((size_t)512 * 1024 * 2);
  u16* xz_bf    = (u16*)take((size_t)BL_TOT * 2048 * 2);
  u16* u_bf     = (u16*)take((size_t)BL_TOT * 1024 * 2);
  u16* xdbl_bf  = (u16*)take((size_t)BL_TOT * 64 * 2);
  u16* delta_bf = (u16*)take((size_t)BL_TOT * 1024 * 2);
  float* xdbl_f = (float*)take((size_t)BL_TOT * 64 * 4);
  float* An2    = (float*)take((size_t)1024 * 16 * 4);    // 64 KB
  float* a0tab  = (float*)take((size_t)1024 * 4);         // 4 KB
  int* gflag    = (int*)take(256);
  u16* y_bf     = delta_bf;  // alias (read-before-write, same-thread dataflow)
  float* xpart  = (float*)hs_bf;   // x_proj K-split partials (8 MB, dead region)

  // choose NCHUNK by available workspace (deterministic: ws_size is fixed)
  const size_t used = (size_t)(p - (char*)d_ws);
  const size_t avail = (ws_size > used) ? ws_size - used : 0;
  const int nchunk = (avail >= (size_t)64 * 262144 + 64 * 16384 + 1024) ? 64 : 32;
  float* hend;
  float* sumd;
  if (nchunk == 32) {            // alias dead regions (hs_bf 8MB == hend 8MB)
    hend = (float*)hs_bf;
    sumd = (float*)win_bf;
  } else {
    hend = (float*)take((size_t)64 * 262144);   // 16 MB
    sumd = (float*)take((size_t)64 * 16384);    // 1 MB
  }

  // fused prep: all casts + A table + geom flag (no memset needed)
  prep_kernel<<<5729, 256, 0, stream>>>(hs, hs_bf, Win, win_bf, Wx, wx_bf,
                                        Wdt, wdt_bf, Wout, wout_bf,
                                        Alog, An2, a0tab, gflag);

  // K1: xz = hs @ Win^T   (8192 x 2048, K=512), BK=64, XCD-swizzled
  gemm_bf16_kernel<1, true, 64><<<dim3(16, 64, 1), 256, 0, stream>>>(
      hs_bf, 512, win_bf, 512, xz_bf, 2048, 2048, 512, nullptr, 0);
  // conv + silu -> u (8192 x 1024)
  conv_silu_kernel<<<2048, 256, 0, stream>>>(xz_bf, convw, convb, u_bf);
  // x_proj: x_dbl = u @ Wx^T (8192 x 64, K=1024), K-split x4, BK=64
  gemm_bf16_kernel<0, false, 64><<<dim3(1, 64, 4), 256, 0, stream>>>(
      u_bf, 1024, wx_bf, 1024, xpart, 64, 64, 256, nullptr, (size_t)BL_TOT * 64);
  // reduce partials -> xdbl_f (f32 for scan) + xdbl_bf (for dt GEMM)
  reduce_xdbl_kernel<<<512, 256, 0, stream>>>(xpart, xdbl_f, xdbl_bf);
  // delta = softplus(dt_low @ Wdt^T + b_dt) (8192 x 1024, K=32), BK=32
  gemm_bf16_kernel<2, true, 32><<<dim3(8, 64, 1), 256, 0, stream>>>(
      xdbl_bf, 64, wdt_bf, 32, delta_bf, 1024, 1024, 32, bdt, 0);
  // selective scan (chunked, 128-thread blocks, packed f32x2 math)
  if (nchunk == 64) {
    scan_pass1<32><<<2048, 128, 0, stream>>>(delta_bf, u_bf, xdbl_f, An2, a0tab, gflag, hend, sumd);
    scan_pass2<<<256, 256, 0, stream>>>(An2, sumd, hend, 64);
    scan_pass3<32><<<2048, 128, 0, stream>>>(delta_bf, u_bf, xdbl_f, xz_bf, An2, a0tab, gflag, Dv, hend, y_bf);
  } else {
    scan_pass1<64><<<1024, 128, 0, stream>>>(delta_bf, u_bf, xdbl_f, An2, a0tab, gflag, hend, sumd);
    scan_pass2<<<256, 256, 0, stream>>>(An2, sumd, hend, 32);
    scan_pass3<64><<<1024, 128, 0, stream>>>(delta_bf, u_bf, xdbl_f, xz_bf, An2, a0tab, gflag, Dv, hend, y_bf);
  }
  // out = y @ Wout^T (8192 x 512, K=1024) -> f32, BK=64, XCD-swizzled
  gemm_bf16_kernel<0, true, 64><<<dim3(4, 64, 1), 256, 0, stream>>>(
      y_bf, 1024, wout_bf, 1024, d_out, 512, 512, 1024, nullptr, 0);
}

// Round 16
// 180.806 us; speedup vs baseline: 1.0835x; 1.0835x over previous
//
#include <hip/hip_runtime.h>
#include <math.h>

typedef unsigned short u16;
typedef unsigned int u32;
typedef __bf16 bf16x8 __attribute__((ext_vector_type(8)));
typedef float f32x4 __attribute__((ext_vector_type(4)));

// B=4, L=2048, D_MODEL=512, D_INNER=1024, D_STATE=16, D_CONV=4, DT_RANK=32
#define LSEQ 2048
#define BL_TOT 8192            // B*L

#if __has_builtin(__builtin_amdgcn_exp2f)
#define EXP2(x) __builtin_amdgcn_exp2f(x)
#else
#define EXP2(x) exp2f(x)
#endif
#define LOG2E 1.44269504088896f

__device__ __forceinline__ float bf2f(u16 h) { return __uint_as_float(((u32)h) << 16); }
__device__ __forceinline__ u16 f2bf(float f) {
  u32 u = __float_as_uint(f);
  u32 r = (u + 0x7fffu + ((u >> 16) & 1u)) >> 16;
  return (u16)r;
}

// async global->LDS, 16B per lane (lds dest = wave-uniform base + lane*16)
__device__ __forceinline__ void async_cp16(const void* g, void* l) {
  __builtin_amdgcn_global_load_lds(
      (const __attribute__((address_space(1))) unsigned int*)g,
      (__attribute__((address_space(3))) unsigned int*)l, 16, 0, 0);
}

__device__ __forceinline__ void cast4(const float* __restrict__ in,
                                      u16* __restrict__ out, int i) {
  const float4 v = ((const float4*)in)[i];
  uint2 o;
  o.x = (u32)f2bf(v.x) | ((u32)f2bf(v.y) << 16);
  o.y = (u32)f2bf(v.z) | ((u32)f2bf(v.w) << 16);
  ((uint2*)out)[i] = o;
}

// ---------------- fused prep: all input casts + A-table + geom flag --------
__global__ __launch_bounds__(256) void prep_kernel(
    const float* __restrict__ hs, u16* __restrict__ hs_bf,
    const float* __restrict__ Win, u16* __restrict__ win_bf,
    const float* __restrict__ Wx, u16* __restrict__ wx_bf,
    const float* __restrict__ Wdt, u16* __restrict__ wdt_bf,
    const float* __restrict__ Wout, u16* __restrict__ wout_bf,
    const float* __restrict__ A_log, float* __restrict__ An2,
    float* __restrict__ a0tab, int* __restrict__ flag)
{
  const int blk = blockIdx.x;
  const int tid = threadIdx.x;
  if (blk < 4096) {
    cast4(hs, hs_bf, blk * 256 + tid);
  } else if (blk < 5120) {
    cast4(Win, win_bf, (blk - 4096) * 256 + tid);
  } else if (blk < 5184) {
    cast4(Wx, wx_bf, (blk - 5120) * 256 + tid);
  } else if (blk < 5216) {
    cast4(Wdt, wdt_bf, (blk - 5184) * 256 + tid);
  } else if (blk < 5728) {
    cast4(Wout, wout_bf, (blk - 5216) * 256 + tid);
  } else {
    const int i = (blk - 5728) * 256 + tid;       // 0..16383
    const float v = -__expf(A_log[i]) * LOG2E;
    An2[i] = v;
    const int d = i >> 4, n = i & 15;
    const float a0 = -__expf(A_log[d * 16]) * LOG2E;
    if (n == 0) a0tab[d] = a0;
    const float ev = (n + 1) * a0;
    if (fabsf(v - ev) > 4e-6f * fabsf(ev)) atomicAnd(flag, 0);
  }
}

// ---------------- bf16 MFMA GEMM: C[M,N] = A[M,K] * B[N,K]^T ----------------
// 128x128 tile, 4 waves, BK=32 (linear LDS) or BK=64 (XOR-swizzled LDS:
// phys 16B-slot = logical ^ (row&7); write side = pre-swizzled global src,
// read side = same XOR -> 2-way banks, rule #21 both-sides). K-split via
// gridDim.z (kper per slice, czstride = f32 elems per z slice, EPI==0 only).
// SWZ: bijective XCD swizzle of flat block id (needs nwg % 8 == 0).
// EPI: 0 = f32 store, 1 = bf16 store, 2 = softplus(acc + bias[n]) -> bf16
template<int EPI, bool SWZ, int BK>
__global__ __launch_bounds__(256) void gemm_bf16_kernel(
    const u16* __restrict__ A, int lda,
    const u16* __restrict__ B, int ldb,
    void* __restrict__ C, int ldc,
    int N, int kper, const float* __restrict__ bias, size_t czstride)
{
  __shared__ alignas(1024) u16 As[128][BK];
  __shared__ alignas(1024) u16 Bs[128][BK];
  const int tid = threadIdx.x;
  int bx = blockIdx.x, by = blockIdx.y;
  if (SWZ) {
    const u32 gx = gridDim.x;
    const u32 nwg = gx * gridDim.y;
    const u32 flat = (u32)by * gx + bx;
    const u32 cpx = nwg >> 3;
    const u32 swz = (flat & 7) * cpx + (flat >> 3);
    bx = swz % gx;
    by = swz / gx;
  }
  const int row0 = by * 128;
  const int col0 = bx * 128;
  const int kz0 = blockIdx.z * kper;
  const int wave = tid >> 6, lane = tid & 63;
  const int wr = (wave >> 1) * 64;   // wave row offset in tile
  const int wc = (wave & 1) * 64;    // wave col offset in tile
  const int lr = lane & 15, lk = lane >> 4;

  f32x4 acc[4][4] = {};

  if (BK == 64) {
    // staging: wave w rows [w*32,w*32+32), 4 instrs x 1KB (8 rows of 128B).
    // global source PRE-SWIZZLED: logical slot = (lane&7) ^ (row&7)
    const int srow = wave * 32 + (lane >> 3);
    const int scol = ((lane & 7) ^ (lane >> 3)) * 8;
    const u16* ag = A + (size_t)(row0 + srow) * lda + scol;
    const u16* bg = B + (size_t)(col0 + srow) * ldb + scol;
    u16* al = &As[0][0] + wave * 2048;     // u16 elems (wave*4KB)
    u16* bl = &Bs[0][0] + wave * 2048;
    const int lr7 = lr & 7;

    for (int k0 = kz0; k0 < kz0 + kper; k0 += 64) {
      __syncthreads();
      #pragma unroll
      for (int s = 0; s < 4; ++s) {
        async_cp16(ag + (size_t)s * 8 * lda + k0, al + s * 512);
        async_cp16(bg + (size_t)s * 8 * ldb + k0, bl + s * 512);
      }
      __syncthreads();
      bf16x8 af[2][4], bfr[2][4];
      #pragma unroll
      for (int kk = 0; kk < 2; ++kk)
        #pragma unroll
        for (int i = 0; i < 4; ++i) {
          af[kk][i]  = *(const bf16x8*)&As[wr + i * 16 + lr][(((kk << 2) | lk) ^ lr7) * 8];
          bfr[kk][i] = *(const bf16x8*)&Bs[wc + i * 16 + lr][(((kk << 2) | lk) ^ lr7) * 8];
        }
      #pragma unroll
      for (int i = 0; i < 4; ++i)
        #pragma unroll
        for (int j = 0; j < 4; ++j) {
          acc[i][j] = __builtin_amdgcn_mfma_f32_16x16x32_bf16(af[0][i], bfr[0][j], acc[i][j], 0, 0, 0);
          acc[i][j] = __builtin_amdgcn_mfma_f32_16x16x32_bf16(af[1][i], bfr[1][j], acc[i][j], 0, 0, 0);
        }
    }
  } else {
    // BK==32: m97 linear layout (64B rows), 2 instrs/wave/matrix
    const int srow = wave * 32 + (lane >> 2);
    const int scol = (lane & 3) * 8;
    const u16* ag0 = A + (size_t)(row0 + srow) * lda + scol;
    const u16* ag1 = A + (size_t)(row0 + srow + 16) * lda + scol;
    const u16* bg0 = B + (size_t)(col0 + srow) * ldb + scol;
    const u16* bg1 = B + (size_t)(col0 + srow + 16) * ldb + scol;
    u16* al0 = &As[0][0] + wave * 1024;
    u16* al1 = &As[0][0] + wave * 1024 + 512;
    u16* bl0 = &Bs[0][0] + wave * 1024;
    u16* bl1 = &Bs[0][0] + wave * 1024 + 512;

    for (int k0 = kz0; k0 < kz0 + kper; k0 += 32) {
      __syncthreads();
      async_cp16(ag0 + k0, al0);
      async_cp16(ag1 + k0, al1);
      async_cp16(bg0 + k0, bl0);
      async_cp16(bg1 + k0, bl1);
      __syncthreads();
      bf16x8 af[4], bfr[4];
      #pragma unroll
      for (int i = 0; i < 4; ++i) {
        af[i]  = *(const bf16x8*)&As[wr + i * 16 + lr][lk * 8];
        bfr[i] = *(const bf16x8*)&Bs[wc + i * 16 + lr][lk * 8];
      }
      #pragma unroll
      for (int i = 0; i < 4; ++i)
        #pragma unroll
        for (int j = 0; j < 4; ++j)
          acc[i][j] = __builtin_amdgcn_mfma_f32_16x16x32_bf16(af[i], bfr[j], acc[i][j], 0, 0, 0);
    }
  }

  float* Cf = (float*)C + blockIdx.z * czstride;
  // C/D layout (HW-verified): col = lane&15, row = (lane>>4)*4 + reg
  #pragma unroll
  for (int i = 0; i < 4; ++i) {
    #pragma unroll
    for (int j = 0; j < 4; ++j) {
      #pragma unroll
      for (int q = 0; q < 4; ++q) {
        const int r = row0 + wr + i * 16 + lk * 4 + q;
        const int c = col0 + wc + j * 16 + lr;
        if (c < N) {
          float v = acc[i][j][q];
          const size_t o = (size_t)r * ldc + c;
          if (EPI == 0) {
            Cf[o] = v;
          } else if (EPI == 1) {
            ((u16*)C)[o] = f2bf(v);
          } else {
            v += bias[c];
            v = (v > 20.f) ? v : log1pf(__expf(v));
            ((u16*)C)[o] = f2bf(v);
          }
        }
      }
    }
  }
}

// ---------------- reduce 4 K-split partials -> xdbl_f (f32) + xdbl_bf ------
__global__ __launch_bounds__(256) void reduce_xdbl_kernel(
    const float* __restrict__ parts, float* __restrict__ xf, u16* __restrict__ xbf)
{
  const int i = blockIdx.x * 256 + threadIdx.x;   // 131072 float4 slots
  const int S = BL_TOT * 64 / 4;                  // float4 stride per slice
  const float4 a = ((const float4*)parts)[i];
  const float4 b = ((const float4*)parts)[i + S];
  const float4 c = ((const float4*)parts)[i + 2 * S];
  const float4 d = ((const float4*)parts)[i + 3 * S];
  float4 s;
  s.x = (a.x + b.x) + (c.x + d.x);
  s.y = (a.y + b.y) + (c.y + d.y);
  s.z = (a.z + b.z) + (c.z + d.z);
  s.w = (a.w + b.w) + (c.w + d.w);
  ((float4*)xf)[i] = s;
  uint2 o;
  o.x = (u32)f2bf(s.x) | ((u32)f2bf(s.y) << 16);
  o.y = (u32)f2bf(s.z) | ((u32)f2bf(s.w) << 16);
  ((uint2*)xbf)[i] = o;
}

// ---------------- depthwise causal conv1d (k=4) + SiLU ----------------
#define CONV_T 16
__global__ __launch_bounds__(256) void conv_silu_kernel(
    const u16* __restrict__ xz, const float* __restrict__ cw,
    const float* __restrict__ cb, u16* __restrict__ u)
{
  const int d = (blockIdx.x & 3) * 256 + threadIdx.x;
  const int strip = (blockIdx.x >> 2) & (LSEQ / CONV_T - 1);
  const int b = blockIdx.x >> 9;            // 4*128*4 = 2048 blocks
  const int t0 = strip * CONV_T;
  const float4 w = *(const float4*)(cw + d * 4);
  const float bias = cb[d];
  const u16* xp = xz + ((size_t)b * LSEQ + t0) * 2048 + d;
  u16* up = u + ((size_t)b * LSEQ + t0) * 1024 + d;
  float x0 = (t0 >= 3) ? bf2f(xp[-3 * 2048]) : 0.f;
  float x1 = (t0 >= 2) ? bf2f(xp[-2 * 2048]) : 0.f;
  float x2 = (t0 >= 1) ? bf2f(xp[-1 * 2048]) : 0.f;
  #pragma unroll
  for (int t = 0; t < CONV_T; ++t) {
    const float x3 = bf2f(xp[(size_t)t * 2048]);
    float a = bias + x0 * w.x + x1 * w.y + x2 * w.z + x3 * w.w;
    a = a / (1.f + EXP2(a * -LOG2E));
    up[(size_t)t * 1024] = f2bf(a);
    x0 = x1; x1 = x2; x2 = x3;
  }
}

// ---------------- selective scan, chunked, full-channel-per-thread ----------
// One thread owns all 16 states of one (chunk, b, d). Lanes = consecutive d.
// b and the B/C base address derive from blockIdx ONLY (b = (blk&15)>>2) so
// the compiler proves uniformity and emits scalar s_load for B/C rows.
// hend/hinit layout: [chunk][4096 ch][16 n].
template<int CHLEN>
__global__ __launch_bounds__(256) void scan_pass1(
    const u16* __restrict__ delta, const u16* __restrict__ u,
    const float* __restrict__ xdf, const float* __restrict__ An2,
    const float* __restrict__ a0tab, const int* __restrict__ geomflag,
    float* __restrict__ hend, float* __restrict__ sumdelta)
{
  const int chunk = blockIdx.x >> 4;
  const int g = blockIdx.x & 15;
  const int b = g >> 2;                          // uniform (blockIdx only)
  const int d = (g & 3) * 256 + threadIdx.x;     // 0..1023
  const int ch = g * 256 + threadIdx.x;          // b*1024 + d
  const int geom = *geomflag;
  float h[16] = {};
  float sumd = 0.f;
  const size_t base = (size_t)b * LSEQ + (size_t)chunk * CHLEN;  // uniform
  const u16* dp = delta + base * 1024 + d;
  const u16* up = u + base * 1024 + d;
  const float* xd = xdf + base * 64 + 32;   // uniform -> s_load path
  if (geom) {
    const float a0 = a0tab[d];
    #pragma unroll 2
    for (int t = 0; t < CHLEN; ++t) {
      const float dt = bf2f(dp[(size_t)t * 1024]);
      const float ut = bf2f(up[(size_t)t * 1024]);
      const float du = dt * ut;
      const float* bt = xd + (size_t)t * 64;
      const float E = EXP2(dt * a0);
      const float p2 = E * E,  p3 = p2 * E,  p4 = p2 * p2;
      const float p5 = p4 * E, p6 = p4 * p2, p7 = p4 * p3, p8 = p4 * p4;
      const float p9 = p8 * E, p10 = p8 * p2, p11 = p8 * p3, p12 = p8 * p4;
      const float p13 = p8 * p5, p14 = p8 * p6, p15 = p8 * p7, p16 = p8 * p8;
      h[0]  = fmaf(h[0],  E,   du * bt[0]);
      h[1]  = fmaf(h[1],  p2,  du * bt[1]);
      h[2]  = fmaf(h[2],  p3,  du * bt[2]);
      h[3]  = fmaf(h[3],  p4,  du * bt[3]);
      h[4]  = fmaf(h[4],  p5,  du * bt[4]);
      h[5]  = fmaf(h[5],  p6,  du * bt[5]);
      h[6]  = fmaf(h[6],  p7,  du * bt[6]);
      h[7]  = fmaf(h[7],  p8,  du * bt[7]);
      h[8]  = fmaf(h[8],  p9,  du * bt[8]);
      h[9]  = fmaf(h[9],  p10, du * bt[9]);
      h[10] = fmaf(h[10], p11, du * bt[10]);
      h[11] = fmaf(h[11], p12, du * bt[11]);
      h[12] = fmaf(h[12], p13, du * bt[12]);
      h[13] = fmaf(h[13], p14, du * bt[13]);
      h[14] = fmaf(h[14], p15, du * bt[14]);
      h[15] = fmaf(h[15], p16, du * bt[15]);
      sumd += dt;
    }
  } else {
    float A2[16];
    #pragma unroll
    for (int q = 0; q < 4; ++q)
      *(float4*)&A2[4*q] = ((const float4*)(An2 + d * 16))[q];
    for (int t = 0; t < CHLEN; ++t) {
      const float dt = bf2f(dp[(size_t)t * 1024]);
      const float ut = bf2f(up[(size_t)t * 1024]);
      const float du = dt * ut;
      const float* bt = xd + (size_t)t * 64;
      #pragma unroll
      for (int n = 0; n < 16; ++n)
        h[n] = fmaf(h[n], EXP2(dt * A2[n]), du * bt[n]);
      sumd += dt;
    }
  }
  float* he = hend + ((size_t)chunk * 4096 + ch) * 16;
  #pragma unroll
  for (int q = 0; q < 4; ++q)
    ((float4*)he)[q] = make_float4(h[4*q], h[4*q+1], h[4*q+2], h[4*q+3]);
  sumdelta[(size_t)chunk * 4096 + ch] = sumd;
}

// pass2: sequential chunk-stitch, IN PLACE (buf: hend in, hinit out)
__global__ __launch_bounds__(256) void scan_pass2(
    const float* __restrict__ An2, const float* __restrict__ sumdelta,
    float* __restrict__ buf, int nchunk)
{
  const int idx = blockIdx.x * 256 + threadIdx.x;  // 65536 = 4096 ch * 16 n
  const int ch = idx >> 4, n = idx & 15;
  const int d = ch & 1023;
  const float A2 = An2[d * 16 + n];
  float h = 0.f;
  #pragma unroll 4
  for (int c = 0; c < nchunk; ++c) {
    const size_t o = (size_t)c * 4096 + ch;
    const float he = buf[o * 16 + n];
    const float e = EXP2(A2 * sumdelta[o]);   // indep of h -> pipelines ahead
    buf[o * 16 + n] = h;       // hinit for chunk c
    h = e * h + he;
  }
}

// pass3: recompute with correct h_init; y = (<h,C> + u*D) * silu(z) -> bf16
// NOTE: y aliases delta. Safe: each (bl,d) element is read then written by
// the SAME thread (read-before-write, data dependence through the dot).
template<int CHLEN>
__global__ __launch_bounds__(256) void scan_pass3(
    const u16* __restrict__ delta, const u16* __restrict__ u,
    const float* __restrict__ xdf, const u16* __restrict__ xz,
    const float* __restrict__ An2, const float* __restrict__ a0tab,
    const int* __restrict__ geomflag, const float* __restrict__ Dvec,
    const float* __restrict__ hinit, u16* __restrict__ y)
{
  const int chunk = blockIdx.x >> 4;
  const int g = blockIdx.x & 15;
  const int b = g >> 2;                          // uniform (blockIdx only)
  const int d = (g & 3) * 256 + threadIdx.x;
  const int ch = g * 256 + threadIdx.x;
  const int geom = *geomflag;
  float h[16];
  {
    const float4* hi = (const float4*)(hinit + ((size_t)chunk * 4096 + ch) * 16);
    #pragma unroll
    for (int q = 0; q < 4; ++q) *(float4*)&h[4*q] = hi[q];
  }
  const float Dd = Dvec[d];
  const size_t base = (size_t)b * LSEQ + (size_t)chunk * CHLEN;  // uniform
  const u16* dp = delta + base * 1024 + d;
  const u16* up = u + base * 1024 + d;
  const float* xd = xdf + base * 64 + 32;   // uniform -> s_load path
  const u16* zp = xz + base * 2048 + 1024 + d;
  u16* yp = y + base * 1024 + d;
  if (geom) {
    const float a0 = a0tab[d];
    #pragma unroll 2
    for (int t = 0; t < CHLEN; ++t) {
      const float dt = bf2f(dp[(size_t)t * 1024]);
      const float ut = bf2f(up[(size_t)t * 1024]);
      const float du = dt * ut;
      const float* bt = xd + (size_t)t * 64;
      const float E = EXP2(dt * a0);
      const float p2 = E * E,  p3 = p2 * E,  p4 = p2 * p2;
      const float p5 = p4 * E, p6 = p4 * p2, p7 = p4 * p3, p8 = p4 * p4;
      const float p9 = p8 * E, p10 = p8 * p2, p11 = p8 * p3, p12 = p8 * p4;
      const float p13 = p8 * p5, p14 = p8 * p6, p15 = p8 * p7, p16 = p8 * p8;
      float av0, av1, av2, av3;
      h[0]  = fmaf(h[0],  E,   du * bt[0]);  av0 = h[0]  * bt[16];
      h[1]  = fmaf(h[1],  p2,  du * bt[1]);  av1 = h[1]  * bt[17];
      h[2]  = fmaf(h[2],  p3,  du * bt[2]);  av2 = h[2]  * bt[18];
      h[3]  = fmaf(h[3],  p4,  du * bt[3]);  av3 = h[3]  * bt[19];
      h[4]  = fmaf(h[4],  p5,  du * bt[4]);  av0 = fmaf(h[4],  bt[20], av0);
      h[5]  = fmaf(h[5],  p6,  du * bt[5]);  av1 = fmaf(h[5],  bt[21], av1);
      h[6]  = fmaf(h[6],  p7,  du * bt[6]);  av2 = fmaf(h[6],  bt[22], av2);
      h[7]  = fmaf(h[7],  p8,  du * bt[7]);  av3 = fmaf(h[7],  bt[23], av3);
      h[8]  = fmaf(h[8],  p9,  du * bt[8]);  av0 = fmaf(h[8],  bt[24], av0);
      h[9]  = fmaf(h[9],  p10, du * bt[9]);  av1 = fmaf(h[9],  bt[25], av1);
      h[10] = fmaf(h[10], p11, du * bt[10]); av2 = fmaf(h[10], bt[26], av2);
      h[11] = fmaf(h[11], p12, du * bt[11]); av3 = fmaf(h[11], bt[27], av3);
      h[12] = fmaf(h[12], p13, du * bt[12]); av0 = fmaf(h[12], bt[28], av0);
      h[13] = fmaf(h[13], p14, du * bt[13]); av1 = fmaf(h[13], bt[29], av1);
      h[14] = fmaf(h[14], p15, du * bt[14]); av2 = fmaf(h[14], bt[30], av2);
      h[15] = fmaf(h[15], p16, du * bt[15]); av3 = fmaf(h[15], bt[31], av3);
      const float pv = (av0 + av1) + (av2 + av3);
      const float z = bf2f(zp[(size_t)t * 2048]);
      const float sig = 1.f / (1.f + EXP2(z * -LOG2E));
      const float yy = (pv + ut * Dd) * (z * sig);
      yp[(size_t)t * 1024] = f2bf(yy);
    }
  } else {
    float A2[16];
    #pragma unroll
    for (int q = 0; q < 4; ++q)
      *(float4*)&A2[4*q] = ((const float4*)(An2 + d * 16))[q];
    for (int t = 0; t < CHLEN; ++t) {
      const float dt = bf2f(dp[(size_t)t * 1024]);
      const float ut = bf2f(up[(size_t)t * 1024]);
      const float du = dt * ut;
      const float* bt = xd + (size_t)t * 64;
      float av0 = 0.f, av1 = 0.f, av2 = 0.f, av3 = 0.f;
      #pragma unroll
      for (int q = 0; q < 4; ++q) {
        h[4*q+0] = fmaf(h[4*q+0], EXP2(dt * A2[4*q+0]), du * bt[4*q+0]);
        h[4*q+1] = fmaf(h[4*q+1], EXP2(dt * A2[4*q+1]), du * bt[4*q+1]);
        h[4*q+2] = fmaf(h[4*q+2], EXP2(dt * A2[4*q+2]), du * bt[4*q+2]);
        h[4*q+3] = fmaf(h[4*q+3], EXP2(dt * A2[4*q+3]), du * bt[4*q+3]);
        av0 = fmaf(h[4*q+0], bt[16 + 4*q+0], av0);
        av1 = fmaf(h[4*q+1], bt[16 + 4*q+1], av1);
        av2 = fmaf(h[4*q+2], bt[16 + 4*q+2], av2);
        av3 = fmaf(h[4*q+3], bt[16 + 4*q+3], av3);
      }
      const float pv = (av0 + av1) + (av2 + av3);
      const float z = bf2f(zp[(size_t)t * 2048]);
      const float sig = 1.f / (1.f + EXP2(z * -LOG2E));
      const float yy = (pv + ut * Dd) * (z * sig);
      yp[(size_t)t * 1024] = f2bf(yy);
    }
  }
}

extern "C" void kernel_launch(void* const* d_in, const int* in_sizes, int n_in,
                              void* d_out, int out_size, void* d_ws, size_t ws_size,
                              hipStream_t stream)
{
  (void)in_sizes; (void)n_in; (void)out_size;
  const float* hs    = (const float*)d_in[0];
  const float* Win   = (const float*)d_in[1];
  const float* convw = (const float*)d_in[2];
  const float* convb = (const float*)d_in[3];
  const float* Wx    = (const float*)d_in[4];
  const float* Wdt   = (const float*)d_in[5];
  const float* bdt   = (const float*)d_in[6];
  const float* Alog  = (const float*)d_in[7];
  const float* Dv    = (const float*)d_in[8];
  const float* Wout  = (const float*)d_in[9];

  char* p = (char*)d_ws;
  auto take = [&](size_t bytes) -> char* {
    char* r = p; p += (bytes + 255) & ~(size_t)255; return r;
  };
  u16* hs_bf    = (u16*)take((size_t)BL_TOT * 512 * 2);   // 8 MB (dead after K1)
  u16* win_bf   = (u16*)take((size_t)2048 * 512 * 2);     // 2 MB (dead after K1)
  u16* wx_bf    = (u16*)take((size_t)64 * 1024 * 2);
  u16* wdt_bf   = (u16*)take((size_t)1024 * 32 * 2);
  u16* wout_bf  = (u16*)take((size_t)512 * 1024 * 2);
  u16* xz_bf    = (u16*)take((size_t)BL_TOT * 2048 * 2);
  u16* u_bf     = (u16*)take((size_t)BL_TOT * 1024 * 2);
  u16* xdbl_bf  = (u16*)take((size_t)BL_TOT * 64 * 2);
  u16* delta_bf = (u16*)take((size_t)BL_TOT * 1024 * 2);
  float* xdbl_f = (float*)take((size_t)BL_TOT * 64 * 4);
  float* An2    = (float*)take((size_t)1024 * 16 * 4);    // 64 KB
  float* a0tab  = (float*)take((size_t)1024 * 4);         // 4 KB
  int* gflag    = (int*)take(256);
  u16* y_bf     = delta_bf;  // alias (read-before-write, same-thread dataflow)
  float* xpart  = (float*)hs_bf;   // x_proj K-split partials (8 MB, dead region)

  // choose NCHUNK by available workspace (deterministic: ws_size is fixed)
  const size_t used = (size_t)(p - (char*)d_ws);
  const size_t avail = (ws_size > used) ? ws_size - used : 0;
  const int nchunk = (avail >= (size_t)64 * 262144 + 64 * 16384 + 1024) ? 64 : 32;
  float* hend;
  float* sumd;
  if (nchunk == 32) {            // alias dead regions (hs_bf 8MB == hend 8MB)
    hend = (float*)hs_bf;
    sumd = (float*)win_bf;
  } else {
    hend = (float*)take((size_t)64 * 262144);   // 16 MB
    sumd = (float*)take((size_t)64 * 16384);    // 1 MB
  }

  // fused prep: all casts + A table + geom flag
  hipMemsetAsync(gflag, 0xFF, 4, stream);
  prep_kernel<<<5792, 256, 0, stream>>>(hs, hs_bf, Win, win_bf, Wx, wx_bf,
                                        Wdt, wdt_bf, Wout, wout_bf,
                                        Alog, An2, a0tab, gflag);

  // K1: xz = hs @ Win^T   (8192 x 2048, K=512), BK=64, XCD-swizzled
  gemm_bf16_kernel<1, true, 64><<<dim3(16, 64, 1), 256, 0, stream>>>(
      hs_bf, 512, win_bf, 512, xz_bf, 2048, 2048, 512, nullptr, 0);
  // conv + silu -> u (8192 x 1024)
  conv_silu_kernel<<<2048, 256, 0, stream>>>(xz_bf, convw, convb, u_bf);
  // x_proj: x_dbl = u @ Wx^T (8192 x 64, K=1024), K-split x4, BK=64
  gemm_bf16_kernel<0, false, 64><<<dim3(1, 64, 4), 256, 0, stream>>>(
      u_bf, 1024, wx_bf, 1024, xpart, 64, 64, 256, nullptr, (size_t)BL_TOT * 64);
  // reduce partials -> xdbl_f (f32 for scan) + xdbl_bf (for dt GEMM)
  reduce_xdbl_kernel<<<512, 256, 0, stream>>>(xpart, xdbl_f, xdbl_bf);
  // delta = softplus(dt_low @ Wdt^T + b_dt) (8192 x 1024, K=32), BK=32
  gemm_bf16_kernel<2, true, 32><<<dim3(8, 64, 1), 256, 0, stream>>>(
      xdbl_bf, 64, wdt_bf, 32, delta_bf, 1024, 1024, 32, bdt, 0);
  // selective scan (chunked, full channel per thread, hoisted geom flag)
  if (nchunk == 64) {
    scan_pass1<32><<<1024, 256, 0, stream>>>(delta_bf, u_bf, xdbl_f, An2, a0tab, gflag, hend, sumd);
    scan_pass2<<<256, 256, 0, stream>>>(An2, sumd, hend, 64);
    scan_pass3<32><<<1024, 256, 0, stream>>>(delta_bf, u_bf, xdbl_f, xz_bf, An2, a0tab, gflag, Dv, hend, y_bf);
  } else {
    scan_pass1<64><<<512, 256, 0, stream>>>(delta_bf, u_bf, xdbl_f, An2, a0tab, gflag, hend, sumd);
    scan_pass2<<<256, 256, 0, stream>>>(An2, sumd, hend, 32);
    scan_pass3<64><<<512, 256, 0, stream>>>(delta_bf, u_bf, xdbl_f, xz_bf, An2, a0tab, gflag, Dv, hend, y_bf);
  }
  // out = y @ Wout^T (8192 x 512, K=1024) -> f32, BK=64, XCD-swizzled
  gemm_bf16_kernel<0, true, 64><<<dim3(4, 64, 1), 256, 0, stream>>>(
      y_bf, 1024, wout_bf, 1024, d_out, 512, 512, 1024, nullptr, 0);
}